// Round 9
// baseline (1735.406 us; speedup 1.0000x reference)
//
#include <hip/hip_runtime.h>

#define NN 100000
#define NE 3200000
#define NB 391             // ceil(NN/256)
#define NBIN3 782          // ceil(NN/128)
#define BINW3 128          // nodes per bin (power of 2)
#define BCAP3 4608         // per-bin edge capacity: 4092 expected + 8-sigma slack
#define BIN_BLOCKS 512
#define CHUNK 6250         // NE / BIN_BLOCKS exactly

static_assert(NB * 256 >= NN, "NB");
static_assert(NBIN3 * BINW3 >= NN, "BINW3");
static_assert(BIN_BLOCKS * CHUNK == NE, "CHUNK");

__device__ __forceinline__ int wave_incl_scan_i(int v) {
#pragma unroll
  for (int off = 1; off < 64; off <<= 1) {
    int n = __shfl_up(v, off);
    if ((int)(threadIdx.x & 63) >= off) v += n;
  }
  return v;
}

// ---------------- stage 0: per-block per-bin histogram (LDS only) ----------------
__global__ __launch_bounds__(256) void k_hist(const int* __restrict__ ei,
                                              int* __restrict__ hcnt) {
  __shared__ int hist[NBIN3];
  int t = threadIdx.x;
  for (int i = t; i < NBIN3; i += 256) hist[i] = 0;
  __syncthreads();
  int e0 = blockIdx.x * CHUNK;
  for (int e = e0 + t; e < e0 + CHUNK; e += 256)
    atomicAdd(&hist[ei[NE + e] >> 7], 1);
  __syncthreads();
  for (int i = t; i < NBIN3; i += 256) hcnt[blockIdx.x * NBIN3 + i] = hist[i];
}

// ---------------- stage 0b: per-bin column scan over blocks ----------------
__global__ __launch_bounds__(512) void k_hscan(const int* __restrict__ hcnt,
                                               int* __restrict__ hoff,
                                               int* __restrict__ cursor) {
  __shared__ int wsum[8];
  int bin = blockIdx.x;
  int t = threadIdx.x;
  int lane = t & 63, wid = t >> 6;
  int v = hcnt[t * NBIN3 + bin];
  int incl = wave_incl_scan_i(v);
  if (lane == 63) wsum[wid] = incl;
  __syncthreads();
  int base = 0;
  for (int w = 0; w < wid; ++w) base += wsum[w];
  hoff[t * NBIN3 + bin] = base + incl - v;
  if (t == 511) cursor[bin] = base + incl;
}

// ---------------- stage 1: scatter edges into bins (LDS running counters) ----------------
// Packs (dst&127)<<17 | src into one u32 (src < 2^17). Intra-bin order arbitrary
// (aggregation is an order-independent sum).
__global__ __launch_bounds__(256) void k_bin3(const int* __restrict__ ei,
                                              const int* __restrict__ hoff,
                                              unsigned int* __restrict__ binE) {
  __shared__ int run[NBIN3];
  int t = threadIdx.x;
  for (int i = t; i < NBIN3; i += 256) run[i] = hoff[blockIdx.x * NBIN3 + i];
  __syncthreads();
  int e0 = blockIdx.x * CHUNK;
  for (int e = e0 + t; e < e0 + CHUNK; e += 256) {
    int s = ei[e];
    int d = ei[NE + e];
    int bin = d >> 7;
    int slot = atomicAdd(&run[bin], 1);
    binE[(size_t)bin * BCAP3 + slot] = ((unsigned)(d & 127) << 17) | (unsigned)s;
  }
}

// ---------------- softmax aggregation: one block per 128-node bin, LDS accumulators ----------------
__global__ __launch_bounds__(256) void k_aggr_lds(const int* __restrict__ cursor,
                                                  const unsigned int* __restrict__ binE,
                                                  const float* __restrict__ Xn,
                                                  float* __restrict__ Bv) {
  __shared__ float se_l[16 * BINW3];  // [c][dl] -> bank = dl%32
  __shared__ float sm_l[16 * BINW3];
  int t = threadIdx.x;
  int bin = blockIdx.x;
  for (int i = t; i < 16 * BINW3; i += 256) {
    se_l[i] = 0.f;
    sm_l[i] = 0.f;
  }
  __syncthreads();
  int cnt = cursor[bin];
  const unsigned int* be = binE + (size_t)bin * BCAP3;
  for (int i = t; i < cnt; i += 256) {
    unsigned int v = be[i];
    int src = (int)(v & 0x1FFFFu);
    int dl = (int)(v >> 17);
    const float4* xr = reinterpret_cast<const float4*>(Xn + (size_t)src * 16);
#pragma unroll
    for (int q = 0; q < 4; ++q) {
      float4 xv = xr[q];
      float xs[4] = {xv.x, xv.y, xv.z, xv.w};
#pragma unroll
      for (int j = 0; j < 4; ++j) {
        int c = q * 4 + j;
        float m = (xs[j] > 0.f ? xs[j] : 0.f) + 1e-7f;
        float e = __expf(m);
        atomicAdd(&se_l[c * BINW3 + dl], e);
        atomicAdd(&sm_l[c * BINW3 + dl], e * m);
      }
    }
  }
  __syncthreads();
  // write out: Bv[d][c], coalesced over j = dl*16 + c
  for (int j = t; j < BINW3 * 16; j += 256) {
    int dl = j >> 4;
    int c = j & 15;
    int d = bin * BINW3 + dl;
    if (d < NN) {
      float se = se_l[c * BINW3 + dl];
      Bv[(size_t)d * 16 + c] = (se > 0.f) ? (sm_l[c * BINW3 + dl] / se) : 0.f;
    }
  }
}

// ---------------- scans for mask compaction ----------------
template <bool NONZERO>
__global__ __launch_bounds__(256) void k_block_sum(const int* __restrict__ in, int n,
                                                   int* __restrict__ out) {
  __shared__ int ws[4];
  int i = blockIdx.x * 256 + threadIdx.x;
  int v = 0;
  if (i < n) v = NONZERO ? (in[i] != 0 ? 1 : 0) : in[i];
#pragma unroll
  for (int off = 32; off >= 1; off >>= 1) v += __shfl_down(v, off);
  int lane = threadIdx.x & 63, wid = threadIdx.x >> 6;
  if (lane == 0) ws[wid] = v;
  __syncthreads();
  if (threadIdx.x == 0) out[blockIdx.x] = ws[0] + ws[1] + ws[2] + ws[3];
}

__global__ __launch_bounds__(512) void k_scan_small(const int* __restrict__ in, int n,
                                                    int* __restrict__ out) {
  __shared__ int wsum[8];
  int t = threadIdx.x;
  int v = (t < n) ? in[t] : 0;
  int incl = wave_incl_scan_i(v);
  int lane = t & 63, wid = t >> 6;
  if (lane == 63) wsum[wid] = incl;
  __syncthreads();
  int base = 0;
  for (int w = 0; w < wid; ++w) base += wsum[w];
  if (t < n) out[t] = base + incl - v;
}

// ---------------- node transform: A = x @ W_src + b_src ----------------
__global__ __launch_bounds__(256) void k_lin(const float* __restrict__ x,
                                             const float* __restrict__ Wsrc,
                                             const float* __restrict__ bsrc,
                                             float* __restrict__ A) {
  __shared__ float4 Wl[512];  // W[k][c] as float4 over c
  __shared__ float bl[16];
  int t = threadIdx.x;
  for (int i = t; i < 512; i += 256) Wl[i] = reinterpret_cast<const float4*>(Wsrc)[i];
  if (t < 16) bl[t] = bsrc[t];
  __syncthreads();
  int node = blockIdx.x * 256 + t;
  if (node >= NN) return;
  float acc[16];
#pragma unroll
  for (int c = 0; c < 16; ++c) acc[c] = bl[c];
  const float4* x4 = reinterpret_cast<const float4*>(x) + (size_t)node * 32;
#pragma unroll 4
  for (int k4 = 0; k4 < 32; ++k4) {
    float4 xv = x4[k4];
    float xs[4];
    xs[0] = xv.x; xs[1] = xv.y; xs[2] = xv.z; xs[3] = xv.w;
#pragma unroll
    for (int j = 0; j < 4; ++j) {
      const float4* wr = &Wl[(k4 * 4 + j) * 4];
      float s = xs[j];
#pragma unroll
      for (int c4 = 0; c4 < 4; ++c4) {
        float4 w = wr[c4];
        acc[c4 * 4 + 0] = fmaf(s, w.x, acc[c4 * 4 + 0]);
        acc[c4 * 4 + 1] = fmaf(s, w.y, acc[c4 * 4 + 1]);
        acc[c4 * 4 + 2] = fmaf(s, w.z, acc[c4 * 4 + 2]);
        acc[c4 * 4 + 3] = fmaf(s, w.w, acc[c4 * 4 + 3]);
      }
    }
  }
  float4* a4 = reinterpret_cast<float4*>(A + (size_t)node * 16);
#pragma unroll
  for (int q = 0; q < 4; ++q)
    a4[q] = make_float4(acc[q * 4], acc[q * 4 + 1], acc[q * 4 + 2], acc[q * 4 + 3]);
}

// ---------------- MLP stage 1: mid = (aggr + x) @ W1 + b1, plus BN partial stats ----------------
__global__ __launch_bounds__(256) void k_mid(const float* __restrict__ A,
                                             const float* __restrict__ Bv,
                                             const float* __restrict__ W1,
                                             const float* __restrict__ b1,
                                             float* __restrict__ D, float* __restrict__ P) {
  __shared__ float W1l[512];
  __shared__ float b1l[32];
  __shared__ float red[256];
  int t = threadIdx.x;
  for (int i = t; i < 512; i += 256) W1l[i] = W1[i];
  if (t < 32) b1l[t] = b1[t];
  __syncthreads();
  int node = blockIdx.x * 256 + t;
  bool act = node < NN;
  float h[16];
  if (act) {
    const float4* a4 = reinterpret_cast<const float4*>(A + (size_t)node * 16);
    const float4* g4 = reinterpret_cast<const float4*>(Bv + (size_t)node * 16);
#pragma unroll
    for (int q = 0; q < 4; ++q) {
      float4 av = a4[q], gv = g4[q];
      h[q * 4 + 0] = av.x + gv.x;
      h[q * 4 + 1] = av.y + gv.y;
      h[q * 4 + 2] = av.z + gv.z;
      h[q * 4 + 3] = av.w + gv.w;
    }
  } else {
#pragma unroll
    for (int c = 0; c < 16; ++c) h[c] = 0.f;
  }
  float mid[32];
#pragma unroll
  for (int j = 0; j < 32; ++j) mid[j] = b1l[j];
#pragma unroll
  for (int c = 0; c < 16; ++c) {
    float hv = h[c];
    const float4* wr = reinterpret_cast<const float4*>(W1l + c * 32);
#pragma unroll
    for (int j4 = 0; j4 < 8; ++j4) {
      float4 w = wr[j4];
      mid[j4 * 4 + 0] = fmaf(hv, w.x, mid[j4 * 4 + 0]);
      mid[j4 * 4 + 1] = fmaf(hv, w.y, mid[j4 * 4 + 1]);
      mid[j4 * 4 + 2] = fmaf(hv, w.z, mid[j4 * 4 + 2]);
      mid[j4 * 4 + 3] = fmaf(hv, w.w, mid[j4 * 4 + 3]);
    }
  }
  if (act) {
    float4* d4 = reinterpret_cast<float4*>(D + (size_t)node * 32);
#pragma unroll
    for (int j4 = 0; j4 < 8; ++j4)
      d4[j4] = make_float4(mid[j4 * 4], mid[j4 * 4 + 1], mid[j4 * 4 + 2], mid[j4 * 4 + 3]);
  }
  int lane = t & 63, wid = t >> 6;
#pragma unroll
  for (int j = 0; j < 32; ++j) {
    float v = act ? mid[j] : 0.f;
    float v2 = v * v;
#pragma unroll
    for (int off = 32; off >= 1; off >>= 1) {
      v += __shfl_down(v, off);
      v2 += __shfl_down(v2, off);
    }
    if (lane == 0) {
      red[wid * 64 + j] = v;
      red[wid * 64 + 32 + j] = v2;
    }
  }
  __syncthreads();
  if (t < 64) P[blockIdx.x * 64 + t] = red[t] + red[64 + t] + red[128 + t] + red[192 + t];
}

// ---------------- fold BN stats into scale/shift ----------------
__global__ __launch_bounds__(64) void k_stats(const float* __restrict__ P,
                                              const float* __restrict__ g,
                                              const float* __restrict__ be,
                                              float* __restrict__ SS) {
  __shared__ float s[64];
  int t = threadIdx.x;
  float acc = 0.f;
  for (int b = 0; b < NB; ++b) acc += P[b * 64 + t];
  s[t] = acc;
  __syncthreads();
  if (t < 32) {
    float mu = s[t] * (1.0f / NN);
    float var = s[32 + t] * (1.0f / NN) - mu * mu;
    float sc = g[t] * rsqrtf(var + 1e-5f);
    SS[t] = sc;
    SS[32 + t] = be[t] - mu * sc;
  }
}

// ---------------- MLP stage 2: h = relu(relu(BN(mid)) @ W2 + b2) ----------------
__global__ __launch_bounds__(256) void k_out(const float* __restrict__ D,
                                             const float* __restrict__ SS,
                                             const float* __restrict__ W2,
                                             const float* __restrict__ b2,
                                             float* __restrict__ A) {
  __shared__ float W2l[512];
  __shared__ float b2l[16];
  __shared__ float ssl[64];
  int t = threadIdx.x;
  for (int i = t; i < 512; i += 256) W2l[i] = W2[i];
  if (t < 16) b2l[t] = b2[t];
  if (t < 64) ssl[t] = SS[t];
  __syncthreads();
  int node = blockIdx.x * 256 + t;
  if (node >= NN) return;
  float m[32];
  const float4* d4 = reinterpret_cast<const float4*>(D + (size_t)node * 32);
#pragma unroll
  for (int j4 = 0; j4 < 8; ++j4) {
    float4 v = d4[j4];
    m[j4 * 4 + 0] = v.x; m[j4 * 4 + 1] = v.y; m[j4 * 4 + 2] = v.z; m[j4 * 4 + 3] = v.w;
  }
  float o[16];
#pragma unroll
  for (int c = 0; c < 16; ++c) o[c] = b2l[c];
#pragma unroll
  for (int j = 0; j < 32; ++j) {
    float tj = fmaf(m[j], ssl[j], ssl[32 + j]);
    tj = tj > 0.f ? tj : 0.f;
    const float4* wr = reinterpret_cast<const float4*>(W2l + j * 16);
#pragma unroll
    for (int c4 = 0; c4 < 4; ++c4) {
      float4 w = wr[c4];
      o[c4 * 4 + 0] = fmaf(tj, w.x, o[c4 * 4 + 0]);
      o[c4 * 4 + 1] = fmaf(tj, w.y, o[c4 * 4 + 1]);
      o[c4 * 4 + 2] = fmaf(tj, w.z, o[c4 * 4 + 2]);
      o[c4 * 4 + 3] = fmaf(tj, w.w, o[c4 * 4 + 3]);
    }
  }
  float4* a4 = reinterpret_cast<float4*>(A + (size_t)node * 16);
#pragma unroll
  for (int q = 0; q < 4; ++q) {
    float4 r;
    r.x = o[q * 4 + 0] > 0.f ? o[q * 4 + 0] : 0.f;
    r.y = o[q * 4 + 1] > 0.f ? o[q * 4 + 1] : 0.f;
    r.z = o[q * 4 + 2] > 0.f ? o[q * 4 + 2] : 0.f;
    r.w = o[q * 4 + 3] > 0.f ? o[q * 4 + 3] : 0.f;
    a4[q] = r;
  }
}

// ---------------- final fc + mask compaction ----------------
__global__ __launch_bounds__(256) void k_fc(const float* __restrict__ H2,
                                            const int* __restrict__ mask,
                                            const int* __restrict__ moff,
                                            const float* __restrict__ fcW,
                                            const float* __restrict__ fcb,
                                            float* __restrict__ outp) {
  __shared__ float fwl[512];
  __shared__ float fbl[32];
  __shared__ int ws[4];
  int t = threadIdx.x;
  for (int i = t; i < 512; i += 256) fwl[i] = fcW[i];
  if (t < 32) fbl[t] = fcb[t];
  __syncthreads();
  int node = blockIdx.x * 256 + t;
  int a = (node < NN && mask[node] != 0) ? 1 : 0;
  int incl = wave_incl_scan_i(a);
  int lane = t & 63, wid = t >> 6;
  if (lane == 63) ws[wid] = incl;
  __syncthreads();
  int base = moff[blockIdx.x];
  for (int w = 0; w < wid; ++w) base += ws[w];
  int pos = base + incl - a;
  if (!a) return;
  float h[16];
  const float4* h4 = reinterpret_cast<const float4*>(H2 + (size_t)node * 16);
#pragma unroll
  for (int q = 0; q < 4; ++q) {
    float4 v = h4[q];
    h[q * 4 + 0] = v.x; h[q * 4 + 1] = v.y; h[q * 4 + 2] = v.z; h[q * 4 + 3] = v.w;
  }
  float o[32];
#pragma unroll
  for (int k = 0; k < 32; ++k) o[k] = fbl[k];
#pragma unroll
  for (int c = 0; c < 16; ++c) {
    float hv = h[c];
    const float4* wr = reinterpret_cast<const float4*>(fwl + c * 32);
#pragma unroll
    for (int k4 = 0; k4 < 8; ++k4) {
      float4 w = wr[k4];
      o[k4 * 4 + 0] = fmaf(hv, w.x, o[k4 * 4 + 0]);
      o[k4 * 4 + 1] = fmaf(hv, w.y, o[k4 * 4 + 1]);
      o[k4 * 4 + 2] = fmaf(hv, w.z, o[k4 * 4 + 2]);
      o[k4 * 4 + 3] = fmaf(hv, w.w, o[k4 * 4 + 3]);
    }
  }
  float4* op = reinterpret_cast<float4*>(outp + (size_t)pos * 32);
#pragma unroll
  for (int q = 0; q < 8; ++q)
    op[q] = make_float4(o[q * 4], o[q * 4 + 1], o[q * 4 + 2], o[q * 4 + 3]);
}

extern "C" void kernel_launch(void* const* d_in, const int* in_sizes, int n_in,
                              void* d_out, int out_size, void* d_ws, size_t ws_size,
                              hipStream_t stream) {
  const int* ei = (const int*)d_in[1];       // edge_index [2][E] (int32 per harness)
  const float* x = (const float*)d_in[3];    // [N][128]
  const int* mask = (const int*)d_in[4];     // [N]
  const float* Wsrc = (const float*)d_in[5];
  const float* bsrc = (const float*)d_in[6];
  const float* c1W1 = (const float*)d_in[7];
  const float* c1b1 = (const float*)d_in[8];
  const float* c1g = (const float*)d_in[9];
  const float* c1be = (const float*)d_in[10];
  const float* c1W2 = (const float*)d_in[11];
  const float* c1b2 = (const float*)d_in[12];
  const float* c2W1 = (const float*)d_in[13];
  const float* c2b1 = (const float*)d_in[14];
  const float* c2g = (const float*)d_in[15];
  const float* c2be = (const float*)d_in[16];
  const float* c2W2 = (const float*)d_in[17];
  const float* c2b2 = (const float*)d_in[18];
  const float* fcW = (const float*)d_in[19];
  const float* fcb = (const float*)d_in[20];

  char* wp = (char*)d_ws;
  auto nxt = [&](size_t bytes) {
    char* p = wp;
    wp += (bytes + 255) & ~(size_t)255;
    return p;
  };
  float* A = (float*)nxt((size_t)NN * 16 * 4);    // x1 / h1 / h2
  float* Bv = (float*)nxt((size_t)NN * 16 * 4);   // aggr
  float* D = (float*)nxt((size_t)NN * 32 * 4);    // MLP hidden
  float* P = (float*)nxt((size_t)NB * 64 * 4);    // BN partials
  float* SS = (float*)nxt(64 * 4);                // folded scale/shift
  int* cursor = (int*)nxt((size_t)NBIN3 * 4);
  unsigned int* binE = (unsigned int*)nxt((size_t)NBIN3 * BCAP3 * 4);
  int* hcnt = (int*)nxt((size_t)BIN_BLOCKS * NBIN3 * 4);
  int* hoff = (int*)nxt((size_t)BIN_BLOCKS * NBIN3 * 4);
  int* mcnt = (int*)nxt((size_t)NB * 4);
  int* moff = (int*)nxt((size_t)NB * 4);

  // edge binning (built once, reused by both convs); no global atomics anywhere
  k_hist<<<BIN_BLOCKS, 256, 0, stream>>>(ei, hcnt);
  k_hscan<<<NBIN3, 512, 0, stream>>>(hcnt, hoff, cursor);
  k_bin3<<<BIN_BLOCKS, 256, 0, stream>>>(ei, hoff, binE);

  // conv1
  k_lin<<<NB, 256, 0, stream>>>(x, Wsrc, bsrc, A);
  k_aggr_lds<<<NBIN3, 256, 0, stream>>>(cursor, binE, A, Bv);
  k_mid<<<NB, 256, 0, stream>>>(A, Bv, c1W1, c1b1, D, P);
  k_stats<<<1, 64, 0, stream>>>(P, c1g, c1be, SS);
  k_out<<<NB, 256, 0, stream>>>(D, SS, c1W2, c1b2, A);

  // conv2
  k_aggr_lds<<<NBIN3, 256, 0, stream>>>(cursor, binE, A, Bv);
  k_mid<<<NB, 256, 0, stream>>>(A, Bv, c2W1, c2b1, D, P);
  k_stats<<<1, 64, 0, stream>>>(P, c2g, c2be, SS);
  k_out<<<NB, 256, 0, stream>>>(D, SS, c2W2, c2b2, A);

  // mask compaction + final fc
  k_block_sum<true><<<NB, 256, 0, stream>>>(mask, NN, mcnt);
  k_scan_small<<<1, 512, 0, stream>>>(mcnt, NB, moff);
  k_fc<<<NB, 256, 0, stream>>>(A, mask, moff, fcW, fcb, (float*)d_out);
}

// Round 10
// 516.036 us; speedup vs baseline: 3.3630x; 3.3630x over previous
//
#include <hip/hip_runtime.h>

#define NN 100000
#define NE 3200000
#define NB 391             // ceil(NN/256)
#define NBIN3 782          // ceil(NN/128)
#define BINW3 128          // nodes per bin (power of 2)
#define BCAP3 4608         // per-bin edge capacity: 4092 expected + 8-sigma slack
#define BIN_BLOCKS 512
#define CHUNK 6250         // NE / BIN_BLOCKS exactly
#define AGGR4_BLOCKS 1563  // ceil(NN*4/256)

static_assert(NB * 256 >= NN, "NB");
static_assert(NBIN3 * BINW3 >= NN, "BINW3");
static_assert(BIN_BLOCKS * CHUNK == NE, "CHUNK");
static_assert(AGGR4_BLOCKS * 256 >= NN * 4, "AGGR4");

__device__ __forceinline__ int wave_incl_scan_i(int v) {
#pragma unroll
  for (int off = 1; off < 64; off <<= 1) {
    int n = __shfl_up(v, off);
    if ((int)(threadIdx.x & 63) >= off) v += n;
  }
  return v;
}

// ---------------- stage 0: per-block per-bin histogram (LDS only) ----------------
__global__ __launch_bounds__(256) void k_hist(const int* __restrict__ ei,
                                              int* __restrict__ hcnt) {
  __shared__ int hist[NBIN3];
  int t = threadIdx.x;
  for (int i = t; i < NBIN3; i += 256) hist[i] = 0;
  __syncthreads();
  int e0 = blockIdx.x * CHUNK;
  for (int e = e0 + t; e < e0 + CHUNK; e += 256)
    atomicAdd(&hist[ei[NE + e] >> 7], 1);
  __syncthreads();
  for (int i = t; i < NBIN3; i += 256) hcnt[blockIdx.x * NBIN3 + i] = hist[i];
}

// ---------------- stage 0b: per-bin column scan over blocks ----------------
__global__ __launch_bounds__(512) void k_hscan(const int* __restrict__ hcnt,
                                               int* __restrict__ hoff,
                                               int* __restrict__ cursor) {
  __shared__ int wsum[8];
  int bin = blockIdx.x;
  int t = threadIdx.x;
  int lane = t & 63, wid = t >> 6;
  int v = hcnt[t * NBIN3 + bin];
  int incl = wave_incl_scan_i(v);
  if (lane == 63) wsum[wid] = incl;
  __syncthreads();
  int base = 0;
  for (int w = 0; w < wid; ++w) base += wsum[w];
  hoff[t * NBIN3 + bin] = base + incl - v;
  if (t == 511) cursor[bin] = base + incl;
}

// ---------------- stage 1: scatter edges into bins (LDS running counters) ----------------
// Packs (dst&127)<<17 | src into one u32 (src < 2^17).
__global__ __launch_bounds__(256) void k_bin3(const int* __restrict__ ei,
                                              const int* __restrict__ hoff,
                                              unsigned int* __restrict__ binE) {
  __shared__ int run[NBIN3];
  int t = threadIdx.x;
  for (int i = t; i < NBIN3; i += 256) run[i] = hoff[blockIdx.x * NBIN3 + i];
  __syncthreads();
  int e0 = blockIdx.x * CHUNK;
  for (int e = e0 + t; e < e0 + CHUNK; e += 256) {
    int s = ei[e];
    int d = ei[NE + e];
    int bin = d >> 7;
    int slot = atomicAdd(&run[bin], 1);
    binE[(size_t)bin * BCAP3 + slot] = ((unsigned)(d & 127) << 17) | (unsigned)s;
  }
}

// ---------------- stage 1b: scan bin totals -> global bin bases ----------------
__global__ __launch_bounds__(1024) void k_binscan(const int* __restrict__ cursor,
                                                  int* __restrict__ binbase) {
  __shared__ int wsum[16];
  int t = threadIdx.x;
  int v = (t < NBIN3) ? cursor[t] : 0;
  int incl = wave_incl_scan_i(v);
  int lane = t & 63, wid = t >> 6;
  if (lane == 63) wsum[wid] = incl;
  __syncthreads();
  int base = 0;
  for (int w = 0; w < wid; ++w) base += wsum[w];
  if (t < NBIN3) binbase[t] = base + incl - v;
}

// ---------------- stage 2: per-bin LDS counting sort -> rowptr + dst-sorted ssrc ----------------
__global__ __launch_bounds__(256) void k_csr(const int* __restrict__ cursor,
                                             const int* __restrict__ binbase,
                                             const unsigned int* __restrict__ binE,
                                             int* __restrict__ rowptr,
                                             int* __restrict__ ssrc) {
  __shared__ int cnt[BINW3];
  __shared__ int pex[BINW3];
  __shared__ int run[BINW3];
  __shared__ int w0sum;
  int t = threadIdx.x;
  int bin = blockIdx.x;
  int n = cursor[bin];
  int base = binbase[bin];
  if (t < BINW3) cnt[t] = 0;
  __syncthreads();
  const unsigned int* be = binE + (size_t)bin * BCAP3;
  for (int i = t; i < n; i += 256) atomicAdd(&cnt[be[i] >> 17], 1);
  __syncthreads();
  if (t < BINW3) {
    int v = cnt[t];
    int incl = wave_incl_scan_i(v);
    if (t == 63) w0sum = incl;
    pex[t] = incl - v;
  }
  __syncthreads();
  if (t >= 64 && t < BINW3) pex[t] += w0sum;
  __syncthreads();
  if (t < BINW3) {
    int idx = bin * BINW3 + t;
    if (idx <= NN) rowptr[idx] = base + pex[t];
    run[t] = pex[t];
  }
  __syncthreads();
  for (int i = t; i < n; i += 256) {
    unsigned int v = be[i];
    int dl = (int)(v >> 17);
    int slot = atomicAdd(&run[dl], 1);
    ssrc[base + slot] = (int)(v & 0x1FFFFu);
  }
}

// ---------------- scans for mask compaction ----------------
template <bool NONZERO>
__global__ __launch_bounds__(256) void k_block_sum(const int* __restrict__ in, int n,
                                                   int* __restrict__ out) {
  __shared__ int ws[4];
  int i = blockIdx.x * 256 + threadIdx.x;
  int v = 0;
  if (i < n) v = NONZERO ? (in[i] != 0 ? 1 : 0) : in[i];
#pragma unroll
  for (int off = 32; off >= 1; off >>= 1) v += __shfl_down(v, off);
  int lane = threadIdx.x & 63, wid = threadIdx.x >> 6;
  if (lane == 0) ws[wid] = v;
  __syncthreads();
  if (threadIdx.x == 0) out[blockIdx.x] = ws[0] + ws[1] + ws[2] + ws[3];
}

__global__ __launch_bounds__(512) void k_scan_small(const int* __restrict__ in, int n,
                                                    int* __restrict__ out) {
  __shared__ int wsum[8];
  int t = threadIdx.x;
  int v = (t < n) ? in[t] : 0;
  int incl = wave_incl_scan_i(v);
  int lane = t & 63, wid = t >> 6;
  if (lane == 63) wsum[wid] = incl;
  __syncthreads();
  int base = 0;
  for (int w = 0; w < wid; ++w) base += wsum[w];
  if (t < n) out[t] = base + incl - v;
}

// ---------------- node transform: A = x @ W_src + b_src ----------------
__global__ __launch_bounds__(256) void k_lin(const float* __restrict__ x,
                                             const float* __restrict__ Wsrc,
                                             const float* __restrict__ bsrc,
                                             float* __restrict__ A) {
  __shared__ float4 Wl[512];  // W[k][c] as float4 over c
  __shared__ float bl[16];
  int t = threadIdx.x;
  for (int i = t; i < 512; i += 256) Wl[i] = reinterpret_cast<const float4*>(Wsrc)[i];
  if (t < 16) bl[t] = bsrc[t];
  __syncthreads();
  int node = blockIdx.x * 256 + t;
  if (node >= NN) return;
  float acc[16];
#pragma unroll
  for (int c = 0; c < 16; ++c) acc[c] = bl[c];
  const float4* x4 = reinterpret_cast<const float4*>(x) + (size_t)node * 32;
#pragma unroll 4
  for (int k4 = 0; k4 < 32; ++k4) {
    float4 xv = x4[k4];
    float xs[4];
    xs[0] = xv.x; xs[1] = xv.y; xs[2] = xv.z; xs[3] = xv.w;
#pragma unroll
    for (int j = 0; j < 4; ++j) {
      const float4* wr = &Wl[(k4 * 4 + j) * 4];
      float s = xs[j];
#pragma unroll
      for (int c4 = 0; c4 < 4; ++c4) {
        float4 w = wr[c4];
        acc[c4 * 4 + 0] = fmaf(s, w.x, acc[c4 * 4 + 0]);
        acc[c4 * 4 + 1] = fmaf(s, w.y, acc[c4 * 4 + 1]);
        acc[c4 * 4 + 2] = fmaf(s, w.z, acc[c4 * 4 + 2]);
        acc[c4 * 4 + 3] = fmaf(s, w.w, acc[c4 * 4 + 3]);
      }
    }
  }
  float4* a4 = reinterpret_cast<float4*>(A + (size_t)node * 16);
#pragma unroll
  for (int q = 0; q < 4; ++q)
    a4[q] = make_float4(acc[q * 4], acc[q * 4 + 1], acc[q * 4 + 2], acc[q * 4 + 3]);
}

// ---------------- dst-centric softmax aggregation: 4 threads/dst, float4, no atomics ----------------
__global__ __launch_bounds__(256) void k_aggr(const float* __restrict__ Xn,
                                              const int* __restrict__ rowptr,
                                              const int* __restrict__ ssrc,
                                              float* __restrict__ Bout) {
  int gid = blockIdx.x * 256 + threadIdx.x;
  int d = gid >> 2;
  if (d >= NN) return;
  int q = gid & 3;  // channel quad: 4q..4q+3
  int p0 = rowptr[d], p1 = rowptr[d + 1];
  float4 se = make_float4(0.f, 0.f, 0.f, 0.f);
  float4 sm = make_float4(0.f, 0.f, 0.f, 0.f);
  for (int p = p0; p < p1; ++p) {
    int s = ssrc[p];
    float4 v = *reinterpret_cast<const float4*>(Xn + (size_t)s * 16 + q * 4);
    float m0 = (v.x > 0.f ? v.x : 0.f) + 1e-7f;
    float m1 = (v.y > 0.f ? v.y : 0.f) + 1e-7f;
    float m2 = (v.z > 0.f ? v.z : 0.f) + 1e-7f;
    float m3 = (v.w > 0.f ? v.w : 0.f) + 1e-7f;
    float e0 = __expf(m0), e1 = __expf(m1), e2 = __expf(m2), e3 = __expf(m3);
    se.x += e0; se.y += e1; se.z += e2; se.w += e3;
    sm.x = fmaf(e0, m0, sm.x);
    sm.y = fmaf(e1, m1, sm.y);
    sm.z = fmaf(e2, m2, sm.z);
    sm.w = fmaf(e3, m3, sm.w);
  }
  float4 r;
  if (p1 > p0) {
    r.x = sm.x / se.x; r.y = sm.y / se.y; r.z = sm.z / se.z; r.w = sm.w / se.w;
  } else {
    r = make_float4(0.f, 0.f, 0.f, 0.f);
  }
  *reinterpret_cast<float4*>(Bout + (size_t)d * 16 + q * 4) = r;
}

// ---------------- MLP stage 1: mid = (aggr + x) @ W1 + b1, plus BN partial stats ----------------
__global__ __launch_bounds__(256) void k_mid(const float* __restrict__ A,
                                             const float* __restrict__ Bv,
                                             const float* __restrict__ W1,
                                             const float* __restrict__ b1,
                                             float* __restrict__ D, float* __restrict__ P) {
  __shared__ float W1l[512];
  __shared__ float b1l[32];
  __shared__ float red[256];
  int t = threadIdx.x;
  for (int i = t; i < 512; i += 256) W1l[i] = W1[i];
  if (t < 32) b1l[t] = b1[t];
  __syncthreads();
  int node = blockIdx.x * 256 + t;
  bool act = node < NN;
  float h[16];
  if (act) {
    const float4* a4 = reinterpret_cast<const float4*>(A + (size_t)node * 16);
    const float4* g4 = reinterpret_cast<const float4*>(Bv + (size_t)node * 16);
#pragma unroll
    for (int q = 0; q < 4; ++q) {
      float4 av = a4[q], gv = g4[q];
      h[q * 4 + 0] = av.x + gv.x;
      h[q * 4 + 1] = av.y + gv.y;
      h[q * 4 + 2] = av.z + gv.z;
      h[q * 4 + 3] = av.w + gv.w;
    }
  } else {
#pragma unroll
    for (int c = 0; c < 16; ++c) h[c] = 0.f;
  }
  float mid[32];
#pragma unroll
  for (int j = 0; j < 32; ++j) mid[j] = b1l[j];
#pragma unroll
  for (int c = 0; c < 16; ++c) {
    float hv = h[c];
    const float4* wr = reinterpret_cast<const float4*>(W1l + c * 32);
#pragma unroll
    for (int j4 = 0; j4 < 8; ++j4) {
      float4 w = wr[j4];
      mid[j4 * 4 + 0] = fmaf(hv, w.x, mid[j4 * 4 + 0]);
      mid[j4 * 4 + 1] = fmaf(hv, w.y, mid[j4 * 4 + 1]);
      mid[j4 * 4 + 2] = fmaf(hv, w.z, mid[j4 * 4 + 2]);
      mid[j4 * 4 + 3] = fmaf(hv, w.w, mid[j4 * 4 + 3]);
    }
  }
  if (act) {
    float4* d4 = reinterpret_cast<float4*>(D + (size_t)node * 32);
#pragma unroll
    for (int j4 = 0; j4 < 8; ++j4)
      d4[j4] = make_float4(mid[j4 * 4], mid[j4 * 4 + 1], mid[j4 * 4 + 2], mid[j4 * 4 + 3]);
  }
  int lane = t & 63, wid = t >> 6;
#pragma unroll
  for (int j = 0; j < 32; ++j) {
    float v = act ? mid[j] : 0.f;
    float v2 = v * v;
#pragma unroll
    for (int off = 32; off >= 1; off >>= 1) {
      v += __shfl_down(v, off);
      v2 += __shfl_down(v2, off);
    }
    if (lane == 0) {
      red[wid * 64 + j] = v;
      red[wid * 64 + 32 + j] = v2;
    }
  }
  __syncthreads();
  if (t < 64) P[blockIdx.x * 64 + t] = red[t] + red[64 + t] + red[128 + t] + red[192 + t];
}

// ---------------- fold BN stats into scale/shift ----------------
__global__ __launch_bounds__(64) void k_stats(const float* __restrict__ P,
                                              const float* __restrict__ g,
                                              const float* __restrict__ be,
                                              float* __restrict__ SS) {
  __shared__ float s[64];
  int t = threadIdx.x;
  float acc = 0.f;
  for (int b = 0; b < NB; ++b) acc += P[b * 64 + t];
  s[t] = acc;
  __syncthreads();
  if (t < 32) {
    float mu = s[t] * (1.0f / NN);
    float var = s[32 + t] * (1.0f / NN) - mu * mu;
    float sc = g[t] * rsqrtf(var + 1e-5f);
    SS[t] = sc;
    SS[32 + t] = be[t] - mu * sc;
  }
}

// ---------------- MLP stage 2: h = relu(relu(BN(mid)) @ W2 + b2) ----------------
__global__ __launch_bounds__(256) void k_out(const float* __restrict__ D,
                                             const float* __restrict__ SS,
                                             const float* __restrict__ W2,
                                             const float* __restrict__ b2,
                                             float* __restrict__ A) {
  __shared__ float W2l[512];
  __shared__ float b2l[16];
  __shared__ float ssl[64];
  int t = threadIdx.x;
  for (int i = t; i < 512; i += 256) W2l[i] = W2[i];
  if (t < 16) b2l[t] = b2[t];
  if (t < 64) ssl[t] = SS[t];
  __syncthreads();
  int node = blockIdx.x * 256 + t;
  if (node >= NN) return;
  float m[32];
  const float4* d4 = reinterpret_cast<const float4*>(D + (size_t)node * 32);
#pragma unroll
  for (int j4 = 0; j4 < 8; ++j4) {
    float4 v = d4[j4];
    m[j4 * 4 + 0] = v.x; m[j4 * 4 + 1] = v.y; m[j4 * 4 + 2] = v.z; m[j4 * 4 + 3] = v.w;
  }
  float o[16];
#pragma unroll
  for (int c = 0; c < 16; ++c) o[c] = b2l[c];
#pragma unroll
  for (int j = 0; j < 32; ++j) {
    float tj = fmaf(m[j], ssl[j], ssl[32 + j]);
    tj = tj > 0.f ? tj : 0.f;
    const float4* wr = reinterpret_cast<const float4*>(W2l + j * 16);
#pragma unroll
    for (int c4 = 0; c4 < 4; ++c4) {
      float4 w = wr[c4];
      o[c4 * 4 + 0] = fmaf(tj, w.x, o[c4 * 4 + 0]);
      o[c4 * 4 + 1] = fmaf(tj, w.y, o[c4 * 4 + 1]);
      o[c4 * 4 + 2] = fmaf(tj, w.z, o[c4 * 4 + 2]);
      o[c4 * 4 + 3] = fmaf(tj, w.w, o[c4 * 4 + 3]);
    }
  }
  float4* a4 = reinterpret_cast<float4*>(A + (size_t)node * 16);
#pragma unroll
  for (int q = 0; q < 4; ++q) {
    float4 r;
    r.x = o[q * 4 + 0] > 0.f ? o[q * 4 + 0] : 0.f;
    r.y = o[q * 4 + 1] > 0.f ? o[q * 4 + 1] : 0.f;
    r.z = o[q * 4 + 2] > 0.f ? o[q * 4 + 2] : 0.f;
    r.w = o[q * 4 + 3] > 0.f ? o[q * 4 + 3] : 0.f;
    a4[q] = r;
  }
}

// ---------------- final fc + mask compaction ----------------
__global__ __launch_bounds__(256) void k_fc(const float* __restrict__ H2,
                                            const int* __restrict__ mask,
                                            const int* __restrict__ moff,
                                            const float* __restrict__ fcW,
                                            const float* __restrict__ fcb,
                                            float* __restrict__ outp) {
  __shared__ float fwl[512];
  __shared__ float fbl[32];
  __shared__ int ws[4];
  int t = threadIdx.x;
  for (int i = t; i < 512; i += 256) fwl[i] = fcW[i];
  if (t < 32) fbl[t] = fcb[t];
  __syncthreads();
  int node = blockIdx.x * 256 + t;
  int a = (node < NN && mask[node] != 0) ? 1 : 0;
  int incl = wave_incl_scan_i(a);
  int lane = t & 63, wid = t >> 6;
  if (lane == 63) ws[wid] = incl;
  __syncthreads();
  int base = moff[blockIdx.x];
  for (int w = 0; w < wid; ++w) base += ws[w];
  int pos = base + incl - a;
  if (!a) return;
  float h[16];
  const float4* h4 = reinterpret_cast<const float4*>(H2 + (size_t)node * 16);
#pragma unroll
  for (int q = 0; q < 4; ++q) {
    float4 v = h4[q];
    h[q * 4 + 0] = v.x; h[q * 4 + 1] = v.y; h[q * 4 + 2] = v.z; h[q * 4 + 3] = v.w;
  }
  float o[32];
#pragma unroll
  for (int k = 0; k < 32; ++k) o[k] = fbl[k];
#pragma unroll
  for (int c = 0; c < 16; ++c) {
    float hv = h[c];
    const float4* wr = reinterpret_cast<const float4*>(fwl + c * 32);
#pragma unroll
    for (int k4 = 0; k4 < 8; ++k4) {
      float4 w = wr[k4];
      o[k4 * 4 + 0] = fmaf(hv, w.x, o[k4 * 4 + 0]);
      o[k4 * 4 + 1] = fmaf(hv, w.y, o[k4 * 4 + 1]);
      o[k4 * 4 + 2] = fmaf(hv, w.z, o[k4 * 4 + 2]);
      o[k4 * 4 + 3] = fmaf(hv, w.w, o[k4 * 4 + 3]);
    }
  }
  float4* op = reinterpret_cast<float4*>(outp + (size_t)pos * 32);
#pragma unroll
  for (int q = 0; q < 8; ++q)
    op[q] = make_float4(o[q * 4], o[q * 4 + 1], o[q * 4 + 2], o[q * 4 + 3]);
}

extern "C" void kernel_launch(void* const* d_in, const int* in_sizes, int n_in,
                              void* d_out, int out_size, void* d_ws, size_t ws_size,
                              hipStream_t stream) {
  const int* ei = (const int*)d_in[1];       // edge_index [2][E] (int32 per harness)
  const float* x = (const float*)d_in[3];    // [N][128]
  const int* mask = (const int*)d_in[4];     // [N]
  const float* Wsrc = (const float*)d_in[5];
  const float* bsrc = (const float*)d_in[6];
  const float* c1W1 = (const float*)d_in[7];
  const float* c1b1 = (const float*)d_in[8];
  const float* c1g = (const float*)d_in[9];
  const float* c1be = (const float*)d_in[10];
  const float* c1W2 = (const float*)d_in[11];
  const float* c1b2 = (const float*)d_in[12];
  const float* c2W1 = (const float*)d_in[13];
  const float* c2b1 = (const float*)d_in[14];
  const float* c2g = (const float*)d_in[15];
  const float* c2be = (const float*)d_in[16];
  const float* c2W2 = (const float*)d_in[17];
  const float* c2b2 = (const float*)d_in[18];
  const float* fcW = (const float*)d_in[19];
  const float* fcb = (const float*)d_in[20];

  char* wp = (char*)d_ws;
  auto nxt = [&](size_t bytes) {
    char* p = wp;
    wp += (bytes + 255) & ~(size_t)255;
    return p;
  };
  float* A = (float*)nxt((size_t)NN * 16 * 4);    // x1 / h1 / h2
  float* Bv = (float*)nxt((size_t)NN * 16 * 4);   // aggr
  float* D = (float*)nxt((size_t)NN * 32 * 4);    // MLP hidden
  float* P = (float*)nxt((size_t)NB * 64 * 4);    // BN partials
  float* SS = (float*)nxt(64 * 4);                // folded scale/shift
  int* cursor = (int*)nxt((size_t)NBIN3 * 4);
  int* binbase = (int*)nxt((size_t)NBIN3 * 4);
  unsigned int* binE = (unsigned int*)nxt((size_t)NBIN3 * BCAP3 * 4);
  int* hcnt = (int*)nxt((size_t)BIN_BLOCKS * NBIN3 * 4);
  int* hoff = (int*)nxt((size_t)BIN_BLOCKS * NBIN3 * 4);
  int* rowptr = (int*)nxt((size_t)(NN + 1) * 4);
  int* ssrc = (int*)nxt((size_t)NE * 4);
  int* mcnt = (int*)nxt((size_t)NB * 4);
  int* moff = (int*)nxt((size_t)NB * 4);

  // dst-sorted CSR via binning + per-bin LDS counting sort; no global atomics
  k_hist<<<BIN_BLOCKS, 256, 0, stream>>>(ei, hcnt);
  k_hscan<<<NBIN3, 512, 0, stream>>>(hcnt, hoff, cursor);
  k_bin3<<<BIN_BLOCKS, 256, 0, stream>>>(ei, hoff, binE);
  k_binscan<<<1, 1024, 0, stream>>>(cursor, binbase);
  k_csr<<<NBIN3, 256, 0, stream>>>(cursor, binbase, binE, rowptr, ssrc);

  // conv1
  k_lin<<<NB, 256, 0, stream>>>(x, Wsrc, bsrc, A);
  k_aggr<<<AGGR4_BLOCKS, 256, 0, stream>>>(A, rowptr, ssrc, Bv);
  k_mid<<<NB, 256, 0, stream>>>(A, Bv, c1W1, c1b1, D, P);
  k_stats<<<1, 64, 0, stream>>>(P, c1g, c1be, SS);
  k_out<<<NB, 256, 0, stream>>>(D, SS, c1W2, c1b2, A);

  // conv2
  k_aggr<<<AGGR4_BLOCKS, 256, 0, stream>>>(A, rowptr, ssrc, Bv);
  k_mid<<<NB, 256, 0, stream>>>(A, Bv, c2W1, c2b1, D, P);
  k_stats<<<1, 64, 0, stream>>>(P, c2g, c2be, SS);
  k_out<<<NB, 256, 0, stream>>>(D, SS, c2W2, c2b2, A);

  // mask compaction + final fc
  k_block_sum<true><<<NB, 256, 0, stream>>>(mask, NN, mcnt);
  k_scan_small<<<1, 512, 0, stream>>>(mcnt, NB, moff);
  k_fc<<<NB, 256, 0, stream>>>(A, mask, moff, fcW, fcb, (float*)d_out);
}